// Round 2
// baseline (691.196 us; speedup 1.0000x reference)
//
#include <hip/hip_runtime.h>

// ---------------------------------------------------------------------------
// SparseLoRAMoE: out = (gate ⊙ (x @ A_flat^T)) @ Bflat * 0.5
//   N=16384, D=4096, E=8, R=16, C=128, O=4096, TOP_K=2
// Round 1: 4 kernels. router fused with fp32->bf16 x conversion (x read ONCE
// in fp32); g1 is barrier-free/LDS-free per-wave MFMA streaming kernel with
// fused gate epilogue (kc eliminated); g2 unchanged (single-barrier, K=128).
// ---------------------------------------------------------------------------

#define NTOK   16384
#define DDIM   4096
#define NEXP   8
#define CDIM   128
#define ODIM   4096

typedef float  f32x4  __attribute__((ext_vector_type(4)));
typedef __bf16 bf16x8 __attribute__((ext_vector_type(8)));
typedef unsigned short ushort8 __attribute__((ext_vector_type(8)));

__device__ __forceinline__ unsigned short f2bf(float f) {
    union { float f; unsigned u; } v; v.f = f;
    unsigned r = v.u + 0x7FFFu + ((v.u >> 16) & 1u);   // RNE
    return (unsigned short)(r >> 16);
}

// ---------------------------------------------------------------------------
// prep: A [128,4096] f32 -> bf16 (8 elem/thread); Bm [8,4096,16] f32 ->
//       Bt [o][c] bf16 (4 elem/thread, coalesced float4 reads).
// grid 768 x 256
// ---------------------------------------------------------------------------
__global__ void prep_kernel(const float* __restrict__ A,
                            const float* __restrict__ Bm,
                            unsigned short* __restrict__ A_bf,
                            unsigned short* __restrict__ Bt) {
    int t = blockIdx.x * 256 + threadIdx.x;
    if (t < 65536) {                       // A: 524288 elems, 8 per thread
        int idx = t * 8;
        float4 a0 = *(const float4*)(A + idx);
        float4 a1 = *(const float4*)(A + idx + 4);
        ushort8 o;
        o[0] = f2bf(a0.x); o[1] = f2bf(a0.y); o[2] = f2bf(a0.z); o[3] = f2bf(a0.w);
        o[4] = f2bf(a1.x); o[5] = f2bf(a1.y); o[6] = f2bf(a1.z); o[7] = f2bf(a1.w);
        *(ushort8*)(A_bf + idx) = o;
    } else {                               // Bt: 524288 elems, 4 per thread
        int t2 = t - 65536;                // t2 = e*16384 + o*4 + rq
        int e = t2 >> 14;
        int o = (t2 & 16383) >> 2;
        int rq = t2 & 3;
        float4 b = *(const float4*)(Bm + ((size_t)(e * 4096 + o) * 16) + rq * 4);
        ushort4 s;
        s.x = f2bf(b.x); s.y = f2bf(b.y); s.z = f2bf(b.z); s.w = f2bf(b.w);
        *(ushort4*)(Bt + (size_t)o * CDIM + e * 16 + rq * 4) = s;
    }
}

// ---------------------------------------------------------------------------
// router: fp32 logits -> top-2 gates (pre-scaled by 0.5) AND x -> x_bf.
// One wave per 8 tokens; lanes tile D with float4. grid 512 x 256.
// ---------------------------------------------------------------------------
__global__ __launch_bounds__(256) void router_kernel(const float* __restrict__ x,
                                                     const float* __restrict__ rw,
                                                     const float* __restrict__ rbias,
                                                     float* __restrict__ gates,
                                                     unsigned short* __restrict__ xbf) {
    int wv = threadIdx.x >> 6, lane = threadIdx.x & 63;
    int tok0 = blockIdx.x * 32 + wv * 8;
    const float* xb = x + (size_t)tok0 * DDIM;
    unsigned short* xo = xbf + (size_t)tok0 * DDIM;

    float acc[8][8];
    #pragma unroll
    for (int t = 0; t < 8; t++)
        #pragma unroll
        for (int e = 0; e < 8; e++) acc[t][e] = 0.f;

    for (int i = 0; i < 16; i++) {
        int d = i * 256 + lane * 4;
        float4 xv[8];
        #pragma unroll
        for (int t = 0; t < 8; t++)
            xv[t] = *(const float4*)(xb + (size_t)t * DDIM + d);
        #pragma unroll
        for (int t = 0; t < 8; t++) {      // emit bf16 copy (coalesced 512B/row)
            ushort4 s;
            s.x = f2bf(xv[t].x); s.y = f2bf(xv[t].y);
            s.z = f2bf(xv[t].z); s.w = f2bf(xv[t].w);
            *(ushort4*)(xo + (size_t)t * DDIM + d) = s;
        }
        #pragma unroll
        for (int e = 0; e < 8; e++) {
            float4 w4 = *(const float4*)(rw + (size_t)e * DDIM + d);
            #pragma unroll
            for (int t = 0; t < 8; t++)
                acc[t][e] += xv[t].x * w4.x + xv[t].y * w4.y +
                             xv[t].z * w4.z + xv[t].w * w4.w;
        }
    }

    #pragma unroll
    for (int t = 0; t < 8; t++)
        #pragma unroll
        for (int e = 0; e < 8; e++) {
            float v = acc[t][e];
            #pragma unroll
            for (int m = 32; m >= 1; m >>= 1) v += __shfl_xor(v, m, 64);
            acc[t][e] = v;
        }

    if (lane == 0) {
        float rb0[8];
        #pragma unroll
        for (int e = 0; e < 8; e++) rb0[e] = rbias[e];
        #pragma unroll
        for (int t = 0; t < 8; t++) {
            float l[8];
            #pragma unroll
            for (int e = 0; e < 8; e++) l[e] = acc[t][e] + rb0[e];
            int a1 = 0; float m1 = l[0];
            #pragma unroll
            for (int e = 1; e < 8; e++) if (l[e] > m1) { m1 = l[e]; a1 = e; }
            int a2 = -1; float m2 = -3.0e38f;
            #pragma unroll
            for (int e = 0; e < 8; e++) if (e != a1 && l[e] > m2) { m2 = l[e]; a2 = e; }
            float g1 = 1.f / (1.f + expf(m2 - m1));
            float g2 = 1.f - g1;
            float go[8];
            #pragma unroll
            for (int e = 0; e < 8; e++)
                go[e] = (e == a1) ? g1 * 0.5f : ((e == a2) ? g2 * 0.5f : 0.f);
            float4* gp = (float4*)(gates + (size_t)(tok0 + t) * 8);
            gp[0] = make_float4(go[0], go[1], go[2], go[3]);
            gp[1] = make_float4(go[4], go[5], go[6], go[7]);
        }
    }
}

// ---------------------------------------------------------------------------
// g1f: Mg[n][c] = bf16( gate[n][c>>4] * sum_k xbf[n][k]*A_bf[c][k] )
// Barrier-free, LDS-free. grid 256 x 256 (4 waves); wave owns 16 rows, all 8
// col-frags; operands loaded straight from global in MFMA layout (16B/lane).
// A_bf (1MB) stays L1/L2-hot; only xbf (128MB) streams from HBM.
// Depth-2 register prefetch -> compiler pipelines with partial vmcnt waits.
// ---------------------------------------------------------------------------
__global__ __launch_bounds__(256) void g1f_kernel(const unsigned short* __restrict__ xbf,
                                                  const unsigned short* __restrict__ A_bf,
                                                  const float* __restrict__ gates,
                                                  unsigned short* __restrict__ Mg) {
    int tid = threadIdx.x, wv = tid >> 6, lane = tid & 63;
    int row0 = blockIdx.x * 64 + wv * 16;
    int rl = lane & 15, kq = lane >> 4;

    const unsigned short* xp = xbf + (size_t)(row0 + rl) * DDIM + kq * 8;
    const unsigned short* ap = A_bf + (size_t)rl * DDIM + kq * 8;

    f32x4 acc[8];
    #pragma unroll
    for (int f = 0; f < 8; f++) acc[f] = (f32x4){0.f, 0.f, 0.f, 0.f};

    bf16x8 a0, a1, b0[8], b1[8];
    a0 = *(const bf16x8*)(xp);
    #pragma unroll
    for (int f = 0; f < 8; f++) b0[f] = *(const bf16x8*)(ap + (size_t)f * 16 * DDIM);
    a1 = *(const bf16x8*)(xp + 32);
    #pragma unroll
    for (int f = 0; f < 8; f++) b1[f] = *(const bf16x8*)(ap + (size_t)f * 16 * DDIM + 32);

    for (int kt = 0; kt < 126; kt += 2) {
        bf16x8 a2, a3, b2[8], b3[8];
        int o2 = (kt + 2) * 32, o3 = (kt + 3) * 32;
        a2 = *(const bf16x8*)(xp + o2);
        #pragma unroll
        for (int f = 0; f < 8; f++) b2[f] = *(const bf16x8*)(ap + (size_t)f * 16 * DDIM + o2);
        #pragma unroll
        for (int f = 0; f < 8; f++)
            acc[f] = __builtin_amdgcn_mfma_f32_16x16x32_bf16(a0, b0[f], acc[f], 0, 0, 0);
        a3 = *(const bf16x8*)(xp + o3);
        #pragma unroll
        for (int f = 0; f < 8; f++) b3[f] = *(const bf16x8*)(ap + (size_t)f * 16 * DDIM + o3);
        #pragma unroll
        for (int f = 0; f < 8; f++)
            acc[f] = __builtin_amdgcn_mfma_f32_16x16x32_bf16(a1, b1[f], acc[f], 0, 0, 0);
        a0 = a2; a1 = a3;
        #pragma unroll
        for (int f = 0; f < 8; f++) { b0[f] = b2[f]; b1[f] = b3[f]; }
    }
    #pragma unroll
    for (int f = 0; f < 8; f++)
        acc[f] = __builtin_amdgcn_mfma_f32_16x16x32_bf16(a0, b0[f], acc[f], 0, 0, 0);
    #pragma unroll
    for (int f = 0; f < 8; f++)
        acc[f] = __builtin_amdgcn_mfma_f32_16x16x32_bf16(a1, b1[f], acc[f], 0, 0, 0);

    // epilogue: gate (0.5 pre-folded) + bf16 store. C-layout: col=f*16+rl,
    // row=row0+kq*4+r; gate index = col>>4 = f.
    int rbase = row0 + kq * 4;
    #pragma unroll
    for (int r = 0; r < 4; r++) {
        int row = rbase + r;
        const float4* gp = (const float4*)(gates + (size_t)row * 8);
        float4 glo = gp[0], ghi = gp[1];
        float gv[8] = {glo.x, glo.y, glo.z, glo.w, ghi.x, ghi.y, ghi.z, ghi.w};
        #pragma unroll
        for (int f = 0; f < 8; f++)
            Mg[(size_t)row * CDIM + f * 16 + rl] = f2bf(acc[f][r] * gv[f]);
    }
}

// ---------------------------------------------------------------------------
// g2: out[n][o] = sum_c Mg[n][c] * Bt[o][c]  (K=128 single shot, one barrier)
// BM=64, BN=128 -> grid 8192 x 256.
// ---------------------------------------------------------------------------
__global__ __launch_bounds__(256, 2) void g2_kernel(const unsigned short* __restrict__ Mg,
                                                    const unsigned short* __restrict__ Bt,
                                                    float* __restrict__ out) {
    __shared__ alignas(16) unsigned short mt[64 * 136];
    __shared__ alignas(16) unsigned short bt[128 * 136];

    int tid = threadIdx.x, wv = tid >> 6, lane = tid & 63;
    int cb = blockIdx.x & 31, rb = blockIdx.x >> 5;
    int row0 = rb * 64, col0 = cb * 128;

    {
        int r = tid >> 2, q = tid & 3;
        const uint4* src = (const uint4*)(Mg + (size_t)(row0 + r) * CDIM + q * 32);
        uint4 v0 = src[0], v1 = src[1], v2 = src[2], v3 = src[3];
        uint4* dst = (uint4*)(&mt[r * 136 + q * 32]);
        dst[0] = v0; dst[1] = v1; dst[2] = v2; dst[3] = v3;
    }
    {
        int o = tid >> 1, h = tid & 1;
        const uint4* src = (const uint4*)(Bt + (size_t)(col0 + o) * CDIM + h * 64);
        uint4 v0 = src[0], v1 = src[1], v2 = src[2], v3 = src[3];
        uint4 v4 = src[4], v5 = src[5], v6 = src[6], v7 = src[7];
        uint4* dst = (uint4*)(&bt[o * 136 + h * 64]);
        dst[0] = v0; dst[1] = v1; dst[2] = v2; dst[3] = v3;
        dst[4] = v4; dst[5] = v5; dst[6] = v6; dst[7] = v7;
    }
    __syncthreads();

    f32x4 acc[8];
    #pragma unroll
    for (int f = 0; f < 8; f++) acc[f] = (f32x4){0.f, 0.f, 0.f, 0.f};

    int mrow = (wv * 16 + (lane & 15)) * 136;
    int kq = (lane >> 4) * 8;
    #pragma unroll
    for (int kk = 0; kk < 4; kk++) {
        bf16x8 a = *(bf16x8*)(&mt[mrow + kk * 32 + kq]);
        #pragma unroll
        for (int f = 0; f < 8; f++) {
            bf16x8 b = *(bf16x8*)(&bt[(f * 16 + (lane & 15)) * 136 + kk * 32 + kq]);
            acc[f] = __builtin_amdgcn_mfma_f32_16x16x32_bf16(a, b, acc[f], 0, 0, 0);
        }
    }

    int rbase = row0 + wv * 16 + (lane >> 4) * 4;
    int cl = lane & 15;
    #pragma unroll
    for (int f = 0; f < 8; f++)
        #pragma unroll
        for (int r = 0; r < 4; r++)
            out[(size_t)(rbase + r) * ODIM + col0 + f * 16 + cl] = acc[f][r];
}

// ---------------------------------------------------------------------------
extern "C" void kernel_launch(void* const* d_in, const int* in_sizes, int n_in,
                              void* d_out, int out_size, void* d_ws, size_t ws_size,
                              hipStream_t stream) {
    const float* x    = (const float*)d_in[0];
    const float* rw   = (const float*)d_in[1];
    const float* rbia = (const float*)d_in[2];
    const float* A    = (const float*)d_in[3];
    const float* Bm   = (const float*)d_in[4];
    float* out = (float*)d_out;

    char* ws = (char*)d_ws;
    unsigned short* A_bf = (unsigned short*)(ws);                  // 1 MB
    unsigned short* Bt   = (unsigned short*)(ws + (1u << 20));     // 1 MB
    float*          gates= (float*)(ws + (2u << 20));              // 512 KB
    unsigned short* Mg   = (unsigned short*)(ws + (2u << 20) + (1u << 19));          // 4 MB
    unsigned short* xbf  = (unsigned short*)(ws + (6u << 20) + (1u << 19));          // 128 MB

    prep_kernel  <<< 768, 256, 0, stream>>>(A, Bm, A_bf, Bt);
    router_kernel<<< 512, 256, 0, stream>>>(x, rw, rbia, gates, xbf);
    g1f_kernel   <<< 256, 256, 0, stream>>>(xbf, A_bf, gates, Mg);
    g2_kernel    <<<8192, 256, 0, stream>>>(Mg, Bt, out);
}